// Round 3
// baseline (1552.725 us; speedup 1.0000x reference)
//
#include <hip/hip_runtime.h>

#define N_NODES 100000
#define N_EDGES 3200000
#define N_GRAPHS 512
#define F_IN 128
#define F_HID 64
#define F_CAT 192
#define F_OUT 10

// ------------------------------------------------------------- histogram ----
__global__ void deg_kernel(const int* __restrict__ col, int* __restrict__ cnt) {
    int e = blockIdx.x * blockDim.x + threadIdx.x;
    if (e < N_EDGES) atomicAdd(&cnt[col[e]], 1);
}

__global__ void dinv_kernel(const int* __restrict__ cnt, float* __restrict__ dinv) {
    int i = blockIdx.x * blockDim.x + threadIdx.x;
    if (i < N_NODES) {
        int d = cnt[i];
        dinv[i] = d > 0 ? rsqrtf((float)d) : 0.0f;
    }
}

// ------------------------------------------------- two-level prefix scan ----
__global__ void scan1_kernel(const int* __restrict__ cnt, int* __restrict__ start,
                             int* __restrict__ bsum) {
    __shared__ int s[256];
    int t = threadIdx.x;
    int i = blockIdx.x * 256 + t;
    int v = (i < N_NODES) ? cnt[i] : 0;
    s[t] = v;
    __syncthreads();
    for (int o = 1; o < 256; o <<= 1) {
        int x = (t >= o) ? s[t - o] : 0;
        __syncthreads();
        s[t] += x;
        __syncthreads();
    }
    if (i < N_NODES) start[i] = s[t] - v;
    if (t == 255) bsum[blockIdx.x] = s[255];
}

__global__ void scan2_kernel(int* __restrict__ bsum, int nblk) {
    __shared__ int s[512];
    int t = threadIdx.x;  // 512
    int v = (t < nblk) ? bsum[t] : 0;
    s[t] = v;
    __syncthreads();
    for (int o = 1; o < 512; o <<= 1) {
        int x = (t >= o) ? s[t - o] : 0;
        __syncthreads();
        s[t] += x;
        __syncthreads();
    }
    if (t < nblk) bsum[t] = s[t] - v;
}

__global__ void scan3_kernel(int* __restrict__ start, const int* __restrict__ bsum) {
    int i = blockIdx.x * blockDim.x + threadIdx.x;
    if (i < N_NODES) start[i] += bsum[i >> 8];
    if (i == 0) start[N_NODES] = N_EDGES;
}

// ------------------------------------------------------- CSC placement -----
__global__ void place_kernel(const int* __restrict__ row, const int* __restrict__ col,
                             const int* __restrict__ start, int* __restrict__ cursor,
                             int* __restrict__ csr_row) {
    int e = blockIdx.x * blockDim.x + threadIdx.x;
    if (e < N_EDGES) {
        int d = col[e];
        int ofs = atomicAdd(&cursor[d], 1);
        csr_row[start[d] + ofs] = row[e];
    }
}

// ------------------------------------------------------------------ GEMM ----
// HP[N,64] = (X[N,K] @ W[K,64]) * dinv[node].  32 rows/block, 8 rows/thread.
template <int K>
__global__ void gemm_kernel(const float* __restrict__ X, const float* __restrict__ W,
                            const float* __restrict__ dinv, float* __restrict__ HP) {
    __shared__ float Ws[K][64];
    __shared__ float Xs[32][K];
    int tid = threadIdx.x;  // 256
    const float4* W4 = (const float4*)W;
    float4* Ws4 = (float4*)Ws;
    for (int i = tid; i < K * 16; i += 256) Ws4[i] = W4[i];
    int row0 = blockIdx.x * 32;  // exact: 100000 = 32*3125
    const float4* X4 = (const float4*)X;
    float4* Xs4 = (float4*)Xs;
    constexpr int KV = K / 4;
    for (int i = tid; i < 32 * KV; i += 256) {
        int r = i / KV;
        Xs4[i] = X4[(size_t)(row0 + r) * KV + (i - r * KV)];
    }
    __syncthreads();
    int c = tid & 63;
    int rs = tid >> 6;  // 0..3; rows rs+4i
    float acc[8] = {0, 0, 0, 0, 0, 0, 0, 0};
    for (int k = 0; k < K; k += 4) {
        float4 xv[8];
#pragma unroll
        for (int i = 0; i < 8; ++i) xv[i] = *(const float4*)&Xs[rs + 4 * i][k];
#pragma unroll
        for (int kk = 0; kk < 4; ++kk) {
            float w = Ws[k + kk][c];
#pragma unroll
            for (int i = 0; i < 8; ++i) acc[i] += ((const float*)&xv[i])[kk] * w;
        }
    }
#pragma unroll
    for (int i = 0; i < 8; ++i) {
        int gr = row0 + rs + 4 * i;
        HP[(size_t)gr * 64 + c] = acc[i] * dinv[gr];
    }
}

// ------------------------------------------------------------- aggregate ----
// One wave per node; 16 lanes x float4 = 64 feats; 4 edges in parallel/wave.
template <bool WRITE, bool COUNT, int POFF>
__global__ void aggregate_kernel(const int* __restrict__ csr_row, const int* __restrict__ start,
                                 const float4* __restrict__ hp4, const float* __restrict__ dinv,
                                 const float* __restrict__ b, float4* __restrict__ out4,
                                 const int* __restrict__ batch, float* __restrict__ pooled,
                                 float* __restrict__ cntg) {
    int node = blockIdx.x * 4 + (threadIdx.x >> 6);  // exact: 100000 = 4*25000
    int lane = threadIdx.x & 63;
    int sub = lane >> 4;   // edge slot 0..3
    int c4 = lane & 15;    // float4 index
    int s0 = start[node], s1 = start[node + 1];
    float ax0 = 0, ay0 = 0, az0 = 0, aw0 = 0;
    float ax1 = 0, ay1 = 0, az1 = 0, aw1 = 0;
    for (int base = s0 + sub; base < s1; base += 16) {
        int i1 = base + 4;
        int i2 = base + 8;
        int i3 = base + 12;
        {
            float4 v = hp4[(size_t)csr_row[base] * 16 + c4];
            ax0 += v.x; ay0 += v.y; az0 += v.z; aw0 += v.w;
        }
        if (i1 < s1) {
            float4 v = hp4[(size_t)csr_row[i1] * 16 + c4];
            ax1 += v.x; ay1 += v.y; az1 += v.z; aw1 += v.w;
        }
        if (i2 < s1) {
            float4 v = hp4[(size_t)csr_row[i2] * 16 + c4];
            ax0 += v.x; ay0 += v.y; az0 += v.z; aw0 += v.w;
        }
        if (i3 < s1) {
            float4 v = hp4[(size_t)csr_row[i3] * 16 + c4];
            ax1 += v.x; ay1 += v.y; az1 += v.z; aw1 += v.w;
        }
    }
    float sx = ax0 + ax1, sy = ay0 + ay1, sz = az0 + az1, sw = aw0 + aw1;
    // butterfly across the 4 edge-slots (lanes ^16, ^32)
#pragma unroll
    for (int off = 16; off < 64; off <<= 1) {
        sx += __shfl_xor(sx, off);
        sy += __shfl_xor(sy, off);
        sz += __shfl_xor(sz, off);
        sw += __shfl_xor(sw, off);
    }
    if (lane < 16) {
        float dv = dinv[node];
        float4 r;
        r.x = fmaxf(dv * sx + b[4 * c4 + 0], 0.0f);
        r.y = fmaxf(dv * sy + b[4 * c4 + 1], 0.0f);
        r.z = fmaxf(dv * sz + b[4 * c4 + 2], 0.0f);
        r.w = fmaxf(dv * sw + b[4 * c4 + 3], 0.0f);
        if (WRITE) out4[(size_t)node * 16 + c4] = r;
        int g = batch[node];
        float* pb = &pooled[g * F_CAT + POFF + 4 * c4];
        atomicAdd(pb + 0, r.x);
        atomicAdd(pb + 1, r.y);
        atomicAdd(pb + 2, r.z);
        atomicAdd(pb + 3, r.w);
        if (COUNT && lane == 0) atomicAdd(&cntg[g], 1.0f);
    }
}

// ------------------------------------------------------------------ head ----
__global__ void head_kernel(const float* __restrict__ pooled, const float* __restrict__ cnt,
                            const float* __restrict__ Wf, const float* __restrict__ bf,
                            float* __restrict__ out) {
    __shared__ float p[F_CAT];
    __shared__ float logits[F_OUT];
    int g = blockIdx.x;
    int tid = threadIdx.x;  // 64
    float invc = 1.0f / fmaxf(cnt[g], 1.0f);
    for (int i = tid; i < F_CAT; i += 64) p[i] = pooled[g * F_CAT + i] * invc;
    __syncthreads();
    if (tid < F_OUT) {
        float acc = bf[tid];
        for (int k = 0; k < F_CAT; ++k) acc += p[k] * Wf[k * F_OUT + tid];
        logits[tid] = acc;
    }
    __syncthreads();
    if (tid == 0) {
        float m = -1e30f;
        for (int j = 0; j < F_OUT; ++j) m = fmaxf(m, logits[j]);
        float s = 0.0f;
        float ex[F_OUT];
        for (int j = 0; j < F_OUT; ++j) { ex[j] = __expf(logits[j] - m); s += ex[j]; }
        float inv = 1.0f / s;
        for (int j = 0; j < F_OUT; ++j) out[g * F_OUT + j] = ex[j] * inv;
    }
}

// ---------------------------------------------------------------- launch ----
extern "C" void kernel_launch(void* const* d_in, const int* in_sizes, int n_in,
                              void* d_out, int out_size, void* d_ws, size_t ws_size,
                              hipStream_t stream) {
    const float* X0 = (const float*)d_in[0];
    const int* ei = (const int*)d_in[1];
    const int* batch = (const int*)d_in[2];
    const float* W1 = (const float*)d_in[3];
    const float* b1 = (const float*)d_in[4];
    const float* W2 = (const float*)d_in[5];
    const float* b2 = (const float*)d_in[6];
    const float* W3 = (const float*)d_in[7];
    const float* b3 = (const float*)d_in[8];
    const float* Wf = (const float*)d_in[9];
    const float* bf = (const float*)d_in[10];
    float* out = (float*)d_out;

    const int* row = ei;
    const int* col = ei + N_EDGES;

    const int SCAN_BLOCKS = (N_NODES + 255) / 256;  // 391

    // ---- workspace layout (all chunks 16B-aligned) ----
    char* wp = (char*)d_ws;
    int* cnt_i = (int*)wp;      wp += (size_t)N_NODES * 4;
    int* cursor = (int*)wp;     wp += (size_t)N_NODES * 4;
    float* pooled = (float*)wp; wp += (size_t)N_GRAPHS * F_CAT * 4;
    float* cntg = (float*)wp;   wp += (size_t)N_GRAPHS * 4;
    size_t zero_bytes = (size_t)(wp - (char*)d_ws);
    float* dinv = (float*)wp;   wp += (size_t)N_NODES * 4;
    int* start = (int*)wp;      wp += (size_t)(N_NODES + 4) * 4;  // +4 keeps 16B align
    int* bsum = (int*)wp;       wp += (size_t)512 * 4;
    int* csr_row = (int*)wp;    wp += (size_t)N_EDGES * 4;
    float* h = (float*)wp;      wp += (size_t)N_NODES * 64 * 4;
    float* x1 = (float*)wp;     wp += (size_t)N_NODES * 64 * 4;
    float* x2 = (float*)wp;     wp += (size_t)N_NODES * 64 * 4;

    hipMemsetAsync(d_ws, 0, zero_bytes, stream);

    deg_kernel<<<(N_EDGES + 255) / 256, 256, 0, stream>>>(col, cnt_i);
    dinv_kernel<<<(N_NODES + 255) / 256, 256, 0, stream>>>(cnt_i, dinv);
    scan1_kernel<<<SCAN_BLOCKS, 256, 0, stream>>>(cnt_i, start, bsum);
    scan2_kernel<<<1, 512, 0, stream>>>(bsum, SCAN_BLOCKS);
    scan3_kernel<<<(N_NODES + 255) / 256, 256, 0, stream>>>(start, bsum);
    place_kernel<<<(N_EDGES + 255) / 256, 256, 0, stream>>>(row, col, start, cursor, csr_row);

    const int gemm_blocks = N_NODES / 32;  // 3125 exact
    const int agg_blocks = N_NODES / 4;    // 25000 exact

    // ---- layer 1 ----
    gemm_kernel<128><<<gemm_blocks, 256, 0, stream>>>(X0, W1, dinv, h);
    aggregate_kernel<true, true, 0><<<agg_blocks, 256, 0, stream>>>(
        csr_row, start, (const float4*)h, dinv, b1, (float4*)x1, batch, pooled, cntg);
    // ---- layer 2 ----
    gemm_kernel<64><<<gemm_blocks, 256, 0, stream>>>(x1, W2, dinv, h);
    aggregate_kernel<true, false, 64><<<agg_blocks, 256, 0, stream>>>(
        csr_row, start, (const float4*)h, dinv, b2, (float4*)x2, batch, pooled, cntg);
    // ---- layer 3 ----
    gemm_kernel<64><<<gemm_blocks, 256, 0, stream>>>(x2, W3, dinv, h);
    aggregate_kernel<false, false, 128><<<agg_blocks, 256, 0, stream>>>(
        csr_row, start, (const float4*)h, dinv, b3, nullptr, batch, pooled, cntg);
    // ---- head ----
    head_kernel<<<N_GRAPHS, 64, 0, stream>>>(pooled, cntg, Wf, bf, out);
}

// Round 5
// 1090.056 us; speedup vs baseline: 1.4244x; 1.4244x over previous
//
#include <hip/hip_runtime.h>

#define N_NODES 100000
#define N_EDGES 3200000
#define N_GRAPHS 512
#define F_IN 128
#define F_HID 64
#define F_CAT 192
#define F_OUT 10

typedef unsigned short ushort_t;
typedef unsigned int uint_t;

static __device__ __forceinline__ ushort_t f2bf(float f) {
    uint_t u = __float_as_uint(f);
    u = (u + 0x7FFFu + ((u >> 16) & 1u)) >> 16;  // round-to-nearest-even
    return (ushort_t)u;
}
static __device__ __forceinline__ float bf2f(ushort_t h) {
    return __uint_as_float((uint_t)h << 16);
}

// ------------------------------------------------------------- histogram ----
__global__ void deg_kernel(const int* __restrict__ col, int* __restrict__ cnt) {
    int e = blockIdx.x * blockDim.x + threadIdx.x;
    if (e < N_EDGES) atomicAdd(&cnt[col[e]], 1);
}

__global__ void dinv_kernel(const int* __restrict__ cnt, float* __restrict__ dinv) {
    int i = blockIdx.x * blockDim.x + threadIdx.x;
    if (i < N_NODES) {
        int d = cnt[i];
        dinv[i] = d > 0 ? rsqrtf((float)d) : 0.0f;
    }
}

// ------------------------------------------------- two-level prefix scan ----
__global__ void scan1_kernel(const int* __restrict__ cnt, int* __restrict__ start,
                             int* __restrict__ bsum) {
    __shared__ int s[256];
    int t = threadIdx.x;
    int i = blockIdx.x * 256 + t;
    int v = (i < N_NODES) ? cnt[i] : 0;
    s[t] = v;
    __syncthreads();
    for (int o = 1; o < 256; o <<= 1) {
        int x = (t >= o) ? s[t - o] : 0;
        __syncthreads();
        s[t] += x;
        __syncthreads();
    }
    if (i < N_NODES) start[i] = s[t] - v;
    if (t == 255) bsum[blockIdx.x] = s[255];
}

__global__ void scan2_kernel(int* __restrict__ bsum, int nblk) {
    __shared__ int s[512];
    int t = threadIdx.x;  // 512
    int v = (t < nblk) ? bsum[t] : 0;
    s[t] = v;
    __syncthreads();
    for (int o = 1; o < 512; o <<= 1) {
        int x = (t >= o) ? s[t - o] : 0;
        __syncthreads();
        s[t] += x;
        __syncthreads();
    }
    if (t < nblk) bsum[t] = s[t] - v;
}

__global__ void scan3_kernel(int* __restrict__ start, const int* __restrict__ bsum) {
    int i = blockIdx.x * blockDim.x + threadIdx.x;
    if (i < N_NODES) start[i] += bsum[i >> 8];
    if (i == 0) start[N_NODES] = N_EDGES;
}

// ------------------------------------------------------- CSC placement -----
__global__ void place_kernel(const int* __restrict__ row, const int* __restrict__ col,
                             const int* __restrict__ start, int* __restrict__ cursor,
                             int* __restrict__ csr_row) {
    int e = blockIdx.x * blockDim.x + threadIdx.x;
    if (e < N_EDGES) {
        int d = col[e];
        int ofs = atomicAdd(&cursor[d], 1);
        csr_row[start[d] + ofs] = row[e];
    }
}

// ------------------------------------------------------------------ GEMM ----
// HP[N,64] = bf16((X[N,K] @ W[K,64]) * dinv[node]).  16 rows/block (round-2).
template <int K>
__global__ void gemm_kernel(const float* __restrict__ X, const float* __restrict__ W,
                            const float* __restrict__ dinv, ushort_t* __restrict__ HP) {
    __shared__ float Ws[K][64];
    __shared__ float Xs[16][K];
    int tid = threadIdx.x;  // 256
    for (int i = tid; i < K * 64; i += 256) Ws[i / 64][i % 64] = W[i];
    int row0 = blockIdx.x * 16;
    for (int i = tid; i < 16 * K; i += 256) {
        int r = i / K, k = i % K;
        int gr = row0 + r;
        Xs[r][k] = (gr < N_NODES) ? X[(size_t)gr * K + k] : 0.0f;
    }
    __syncthreads();
    int c = tid & 63;
    int rs = tid >> 6;
    for (int r = rs; r < 16; r += 4) {
        float acc = 0.0f;
#pragma unroll
        for (int k = 0; k < K; ++k) acc += Xs[r][k] * Ws[k][c];
        int gr = row0 + r;
        if (gr < N_NODES) HP[(size_t)gr * 64 + c] = f2bf(acc * dinv[gr]);
    }
}

// ------------------------------------------------------------- aggregate ----
// One wave per node, lane = channel; hp rows are bf16 (128B per edge).
template <bool WRITE, bool COUNT, int POFF>
__global__ void aggregate_kernel(const int* __restrict__ csr_row, const int* __restrict__ start,
                                 const ushort_t* __restrict__ hp, const float* __restrict__ dinv,
                                 const float* __restrict__ b, float* __restrict__ out,
                                 const int* __restrict__ batch, float* __restrict__ pooled,
                                 float* __restrict__ cntg) {
    int node = blockIdx.x * 4 + (threadIdx.x >> 6);  // exact: 100000 = 4*25000
    int c = threadIdx.x & 63;
    int s0 = start[node], s1 = start[node + 1];
    float acc = 0.0f;
    int j = s0;
    for (; j + 7 < s1; j += 8) {
        int r0 = csr_row[j + 0];
        int r1 = csr_row[j + 1];
        int r2 = csr_row[j + 2];
        int r3 = csr_row[j + 3];
        int r4 = csr_row[j + 4];
        int r5 = csr_row[j + 5];
        int r6 = csr_row[j + 6];
        int r7 = csr_row[j + 7];
        float v0 = bf2f(hp[r0 * 64 + c]);
        float v1 = bf2f(hp[r1 * 64 + c]);
        float v2 = bf2f(hp[r2 * 64 + c]);
        float v3 = bf2f(hp[r3 * 64 + c]);
        float v4 = bf2f(hp[r4 * 64 + c]);
        float v5 = bf2f(hp[r5 * 64 + c]);
        float v6 = bf2f(hp[r6 * 64 + c]);
        float v7 = bf2f(hp[r7 * 64 + c]);
        acc += ((v0 + v1) + (v2 + v3)) + ((v4 + v5) + (v6 + v7));
    }
    for (; j < s1; ++j) acc += bf2f(hp[csr_row[j] * 64 + c]);
    float v = fmaxf(dinv[node] * acc + b[c], 0.0f);
    if (WRITE) out[(size_t)node * 64 + c] = v;
    int g = batch[node];
    atomicAdd(&pooled[g * F_CAT + POFF + c], v);
    if (COUNT && c == 0) atomicAdd(&cntg[g], 1.0f);
}

// ------------------------------------------------------------------ head ----
__global__ void head_kernel(const float* __restrict__ pooled, const float* __restrict__ cnt,
                            const float* __restrict__ Wf, const float* __restrict__ bf,
                            float* __restrict__ out) {
    __shared__ float p[F_CAT];
    __shared__ float logits[F_OUT];
    int g = blockIdx.x;
    int tid = threadIdx.x;  // 64
    float invc = 1.0f / fmaxf(cnt[g], 1.0f);
    for (int i = tid; i < F_CAT; i += 64) p[i] = pooled[g * F_CAT + i] * invc;
    __syncthreads();
    if (tid < F_OUT) {
        float acc = bf[tid];
        for (int k = 0; k < F_CAT; ++k) acc += p[k] * Wf[k * F_OUT + tid];
        logits[tid] = acc;
    }
    __syncthreads();
    if (tid == 0) {
        float m = -1e30f;
        for (int j = 0; j < F_OUT; ++j) m = fmaxf(m, logits[j]);
        float s = 0.0f;
        float ex[F_OUT];
        for (int j = 0; j < F_OUT; ++j) { ex[j] = __expf(logits[j] - m); s += ex[j]; }
        float inv = 1.0f / s;
        for (int j = 0; j < F_OUT; ++j) out[g * F_OUT + j] = ex[j] * inv;
    }
}

// ---------------------------------------------------------------- launch ----
extern "C" void kernel_launch(void* const* d_in, const int* in_sizes, int n_in,
                              void* d_out, int out_size, void* d_ws, size_t ws_size,
                              hipStream_t stream) {
    const float* X0 = (const float*)d_in[0];
    const int* ei = (const int*)d_in[1];
    const int* batch = (const int*)d_in[2];
    const float* W1 = (const float*)d_in[3];
    const float* b1 = (const float*)d_in[4];
    const float* W2 = (const float*)d_in[5];
    const float* b2 = (const float*)d_in[6];
    const float* W3 = (const float*)d_in[7];
    const float* b3 = (const float*)d_in[8];
    const float* Wf = (const float*)d_in[9];
    const float* bf = (const float*)d_in[10];
    float* out = (float*)d_out;

    const int* row = ei;
    const int* col = ei + N_EDGES;

    const int SCAN_BLOCKS = (N_NODES + 255) / 256;  // 391

    // ---- workspace layout ----
    char* wp = (char*)d_ws;
    int* cnt_i = (int*)wp;      wp += (size_t)N_NODES * 4;
    int* cursor = (int*)wp;     wp += (size_t)N_NODES * 4;
    float* pooled = (float*)wp; wp += (size_t)N_GRAPHS * F_CAT * 4;
    float* cntg = (float*)wp;   wp += (size_t)N_GRAPHS * 4;
    size_t zero_bytes = (size_t)(wp - (char*)d_ws);
    float* dinv = (float*)wp;   wp += (size_t)N_NODES * 4;
    int* start = (int*)wp;      wp += (size_t)(N_NODES + 4) * 4;
    int* bsum = (int*)wp;       wp += (size_t)512 * 4;
    int* csr_row = (int*)wp;    wp += (size_t)N_EDGES * 4;
    ushort_t* h = (ushort_t*)wp; wp += (size_t)N_NODES * 64 * 2;
    float* x1 = (float*)wp;     wp += (size_t)N_NODES * 64 * 4;
    float* x2 = (float*)wp;     wp += (size_t)N_NODES * 64 * 4;

    hipMemsetAsync(d_ws, 0, zero_bytes, stream);

    deg_kernel<<<(N_EDGES + 255) / 256, 256, 0, stream>>>(col, cnt_i);
    dinv_kernel<<<(N_NODES + 255) / 256, 256, 0, stream>>>(cnt_i, dinv);
    scan1_kernel<<<SCAN_BLOCKS, 256, 0, stream>>>(cnt_i, start, bsum);
    scan2_kernel<<<1, 512, 0, stream>>>(bsum, SCAN_BLOCKS);
    scan3_kernel<<<(N_NODES + 255) / 256, 256, 0, stream>>>(start, bsum);
    place_kernel<<<(N_EDGES + 255) / 256, 256, 0, stream>>>(row, col, start, cursor, csr_row);

    const int gemm_blocks = (N_NODES + 15) / 16;
    const int agg_blocks = N_NODES / 4;  // 25000 exact

    // ---- layer 1 ----
    gemm_kernel<128><<<gemm_blocks, 256, 0, stream>>>(X0, W1, dinv, h);
    aggregate_kernel<true, true, 0><<<agg_blocks, 256, 0, stream>>>(
        csr_row, start, h, dinv, b1, x1, batch, pooled, cntg);
    // ---- layer 2 ----
    gemm_kernel<64><<<gemm_blocks, 256, 0, stream>>>(x1, W2, dinv, h);
    aggregate_kernel<true, false, 64><<<agg_blocks, 256, 0, stream>>>(
        csr_row, start, h, dinv, b2, x2, batch, pooled, cntg);
    // ---- layer 3 ----
    gemm_kernel<64><<<gemm_blocks, 256, 0, stream>>>(x2, W3, dinv, h);
    aggregate_kernel<false, false, 128><<<agg_blocks, 256, 0, stream>>>(
        csr_row, start, h, dinv, b3, nullptr, batch, pooled, cntg);
    // ---- head ----
    head_kernel<<<N_GRAPHS, 64, 0, stream>>>(pooled, cntg, Wf, bf, out);
}

// Round 6
// 1067.881 us; speedup vs baseline: 1.4540x; 1.0208x over previous
//
#include <hip/hip_runtime.h>

#define N_NODES 100000
#define N_EDGES 3200000
#define N_GRAPHS 512
#define F_IN 128
#define F_HID 64
#define F_CAT 192
#define F_OUT 10

#define N_CHUNKS 4
#define CHUNK_DIV 25000           // nodes per source-chunk; hp slice = 3.2 MB (fits XCD L2)
#define N_CNT (N_NODES * N_CHUNKS)  // 400000 counters

typedef unsigned short ushort_t;
typedef unsigned int uint_t;

static __device__ __forceinline__ ushort_t f2bf(float f) {
    uint_t u = __float_as_uint(f);
    u = (u + 0x7FFFu + ((u >> 16) & 1u)) >> 16;  // round-to-nearest-even
    return (ushort_t)u;
}
static __device__ __forceinline__ float bf2f(ushort_t h) {
    return __uint_as_float((uint_t)h << 16);
}

// ------------------------------------------- per-(dest,src-chunk) histogram ----
__global__ void deg2_kernel(const int* __restrict__ row, const int* __restrict__ col,
                            int* __restrict__ cnt2) {
    int e = blockIdx.x * blockDim.x + threadIdx.x;
    if (e < N_EDGES) {
        int ch = row[e] / CHUNK_DIV;
        atomicAdd(&cnt2[col[e] * N_CHUNKS + ch], 1);
    }
}

__global__ void dinv_kernel(const int* __restrict__ cnt2, float* __restrict__ dinv) {
    int i = blockIdx.x * blockDim.x + threadIdx.x;
    if (i < N_NODES) {
        int d = cnt2[i * 4] + cnt2[i * 4 + 1] + cnt2[i * 4 + 2] + cnt2[i * 4 + 3];
        dinv[i] = d > 0 ? rsqrtf((float)d) : 0.0f;
    }
}

// ------------------------------------------------- two-level prefix scan ----
// scan over N_CNT = 400000 entries; 1024-entry blocks -> 391 block sums.
__global__ void scan1_kernel(const int* __restrict__ cnt, int* __restrict__ start,
                             int* __restrict__ bsum) {
    __shared__ int s[1024];
    int t = threadIdx.x;  // 1024
    int i = blockIdx.x * 1024 + t;
    int v = (i < N_CNT) ? cnt[i] : 0;
    s[t] = v;
    __syncthreads();
    for (int o = 1; o < 1024; o <<= 1) {
        int x = (t >= o) ? s[t - o] : 0;
        __syncthreads();
        s[t] += x;
        __syncthreads();
    }
    if (i < N_CNT) start[i] = s[t] - v;
    if (t == 1023) bsum[blockIdx.x] = s[1023];
}

__global__ void scan2_kernel(int* __restrict__ bsum, int nblk) {
    __shared__ int s[512];
    int t = threadIdx.x;  // 512
    int v = (t < nblk) ? bsum[t] : 0;
    s[t] = v;
    __syncthreads();
    for (int o = 1; o < 512; o <<= 1) {
        int x = (t >= o) ? s[t - o] : 0;
        __syncthreads();
        s[t] += x;
        __syncthreads();
    }
    if (t < nblk) bsum[t] = s[t] - v;
}

__global__ void scan3_kernel(int* __restrict__ start, const int* __restrict__ bsum) {
    int i = blockIdx.x * blockDim.x + threadIdx.x;
    if (i < N_CNT) start[i] += bsum[i >> 10];
    if (i == 0) start[N_CNT] = N_EDGES;
}

// ------------------------------------------------------- CSC placement -----
// segment of dest d, ordered by source-chunk (order within chunk arbitrary)
__global__ void place_kernel(const int* __restrict__ row, const int* __restrict__ col,
                             const int* __restrict__ start2, int* __restrict__ cursor2,
                             int* __restrict__ csr_row) {
    int e = blockIdx.x * blockDim.x + threadIdx.x;
    if (e < N_EDGES) {
        int r = row[e];
        int d = col[e];
        int slot = d * N_CHUNKS + r / CHUNK_DIV;
        int ofs = atomicAdd(&cursor2[slot], 1);
        csr_row[start2[slot] + ofs] = r;
    }
}

// ------------------------------------------------------------------ GEMM ----
// HP[N,64] = bf16((X[N,K] @ W[K,64]) * dinv[node]).  16 rows/block.
template <int K>
__global__ void gemm_kernel(const float* __restrict__ X, const float* __restrict__ W,
                            const float* __restrict__ dinv, ushort_t* __restrict__ HP) {
    __shared__ float Ws[K][64];
    __shared__ float Xs[16][K];
    int tid = threadIdx.x;  // 256
    for (int i = tid; i < K * 64; i += 256) Ws[i / 64][i % 64] = W[i];
    int row0 = blockIdx.x * 16;
    for (int i = tid; i < 16 * K; i += 256) {
        int r = i / K, k = i % K;
        int gr = row0 + r;
        Xs[r][k] = (gr < N_NODES) ? X[(size_t)gr * K + k] : 0.0f;
    }
    __syncthreads();
    int c = tid & 63;
    int rs = tid >> 6;
    for (int r = rs; r < 16; r += 4) {
        float acc = 0.0f;
#pragma unroll
        for (int k = 0; k < K; ++k) acc += Xs[r][k] * Ws[k][c];
        int gr = row0 + r;
        if (gr < N_NODES) HP[(size_t)gr * 64 + c] = f2bf(acc * dinv[gr]);
    }
}

// ------------------------------------------------------------- aggregate ----
// One wave per node, lane = channel; hp rows bf16; segment is chunk-sorted so
// concurrent waves gather from the same ~3.2MB hp slice (L2-resident).
template <bool WRITE, bool COUNT, int POFF>
__global__ void aggregate_kernel(const int* __restrict__ csr_row, const int* __restrict__ start2,
                                 const ushort_t* __restrict__ hp, const float* __restrict__ dinv,
                                 const float* __restrict__ b, float* __restrict__ out,
                                 const int* __restrict__ batch, float* __restrict__ pooled,
                                 float* __restrict__ cntg) {
    int node = blockIdx.x * 4 + (threadIdx.x >> 6);  // exact: 100000 = 4*25000
    int c = threadIdx.x & 63;
    int s0 = start2[node * N_CHUNKS], s1 = start2[node * N_CHUNKS + N_CHUNKS];
    float acc = 0.0f;
    int j = s0;
    for (; j + 7 < s1; j += 8) {
        int r0 = csr_row[j + 0];
        int r1 = csr_row[j + 1];
        int r2 = csr_row[j + 2];
        int r3 = csr_row[j + 3];
        int r4 = csr_row[j + 4];
        int r5 = csr_row[j + 5];
        int r6 = csr_row[j + 6];
        int r7 = csr_row[j + 7];
        float v0 = bf2f(hp[r0 * 64 + c]);
        float v1 = bf2f(hp[r1 * 64 + c]);
        float v2 = bf2f(hp[r2 * 64 + c]);
        float v3 = bf2f(hp[r3 * 64 + c]);
        float v4 = bf2f(hp[r4 * 64 + c]);
        float v5 = bf2f(hp[r5 * 64 + c]);
        float v6 = bf2f(hp[r6 * 64 + c]);
        float v7 = bf2f(hp[r7 * 64 + c]);
        acc += ((v0 + v1) + (v2 + v3)) + ((v4 + v5) + (v6 + v7));
    }
    for (; j < s1; ++j) acc += bf2f(hp[csr_row[j] * 64 + c]);
    float v = fmaxf(dinv[node] * acc + b[c], 0.0f);
    if (WRITE) out[(size_t)node * 64 + c] = v;
    int g = batch[node];
    atomicAdd(&pooled[g * F_CAT + POFF + c], v);
    if (COUNT && c == 0) atomicAdd(&cntg[g], 1.0f);
}

// ------------------------------------------------------------------ head ----
__global__ void head_kernel(const float* __restrict__ pooled, const float* __restrict__ cnt,
                            const float* __restrict__ Wf, const float* __restrict__ bf,
                            float* __restrict__ out) {
    __shared__ float p[F_CAT];
    __shared__ float logits[F_OUT];
    int g = blockIdx.x;
    int tid = threadIdx.x;  // 64
    float invc = 1.0f / fmaxf(cnt[g], 1.0f);
    for (int i = tid; i < F_CAT; i += 64) p[i] = pooled[g * F_CAT + i] * invc;
    __syncthreads();
    if (tid < F_OUT) {
        float acc = bf[tid];
        for (int k = 0; k < F_CAT; ++k) acc += p[k] * Wf[k * F_OUT + tid];
        logits[tid] = acc;
    }
    __syncthreads();
    if (tid == 0) {
        float m = -1e30f;
        for (int j = 0; j < F_OUT; ++j) m = fmaxf(m, logits[j]);
        float s = 0.0f;
        float ex[F_OUT];
        for (int j = 0; j < F_OUT; ++j) { ex[j] = __expf(logits[j] - m); s += ex[j]; }
        float inv = 1.0f / s;
        for (int j = 0; j < F_OUT; ++j) out[g * F_OUT + j] = ex[j] * inv;
    }
}

// ---------------------------------------------------------------- launch ----
extern "C" void kernel_launch(void* const* d_in, const int* in_sizes, int n_in,
                              void* d_out, int out_size, void* d_ws, size_t ws_size,
                              hipStream_t stream) {
    const float* X0 = (const float*)d_in[0];
    const int* ei = (const int*)d_in[1];
    const int* batch = (const int*)d_in[2];
    const float* W1 = (const float*)d_in[3];
    const float* b1 = (const float*)d_in[4];
    const float* W2 = (const float*)d_in[5];
    const float* b2 = (const float*)d_in[6];
    const float* W3 = (const float*)d_in[7];
    const float* b3 = (const float*)d_in[8];
    const float* Wf = (const float*)d_in[9];
    const float* bf = (const float*)d_in[10];
    float* out = (float*)d_out;

    const int* row = ei;
    const int* col = ei + N_EDGES;

    const int SCAN_BLOCKS = (N_CNT + 1023) / 1024;  // 391

    // ---- workspace layout ----
    char* wp = (char*)d_ws;
    int* cnt2 = (int*)wp;       wp += (size_t)N_CNT * 4;
    int* cursor2 = (int*)wp;    wp += (size_t)N_CNT * 4;
    float* pooled = (float*)wp; wp += (size_t)N_GRAPHS * F_CAT * 4;
    float* cntg = (float*)wp;   wp += (size_t)N_GRAPHS * 4;
    size_t zero_bytes = (size_t)(wp - (char*)d_ws);
    float* dinv = (float*)wp;   wp += (size_t)N_NODES * 4;
    int* start2 = (int*)wp;     wp += (size_t)(N_CNT + 4) * 4;
    int* bsum = (int*)wp;       wp += (size_t)512 * 4;
    int* csr_row = (int*)wp;    wp += (size_t)N_EDGES * 4;
    ushort_t* h = (ushort_t*)wp; wp += (size_t)N_NODES * 64 * 2;
    float* x1 = (float*)wp;     wp += (size_t)N_NODES * 64 * 4;
    float* x2 = (float*)wp;     wp += (size_t)N_NODES * 64 * 4;

    hipMemsetAsync(d_ws, 0, zero_bytes, stream);

    deg2_kernel<<<(N_EDGES + 255) / 256, 256, 0, stream>>>(row, col, cnt2);
    dinv_kernel<<<(N_NODES + 255) / 256, 256, 0, stream>>>(cnt2, dinv);
    scan1_kernel<<<SCAN_BLOCKS, 1024, 0, stream>>>(cnt2, start2, bsum);
    scan2_kernel<<<1, 512, 0, stream>>>(bsum, SCAN_BLOCKS);
    scan3_kernel<<<(N_CNT + 255) / 256, 256, 0, stream>>>(start2, bsum);
    place_kernel<<<(N_EDGES + 255) / 256, 256, 0, stream>>>(row, col, start2, cursor2, csr_row);

    const int gemm_blocks = (N_NODES + 15) / 16;
    const int agg_blocks = N_NODES / 4;  // 25000 exact

    // ---- layer 1 ----
    gemm_kernel<128><<<gemm_blocks, 256, 0, stream>>>(X0, W1, dinv, h);
    aggregate_kernel<true, true, 0><<<agg_blocks, 256, 0, stream>>>(
        csr_row, start2, h, dinv, b1, x1, batch, pooled, cntg);
    // ---- layer 2 ----
    gemm_kernel<64><<<gemm_blocks, 256, 0, stream>>>(x1, W2, dinv, h);
    aggregate_kernel<true, false, 64><<<agg_blocks, 256, 0, stream>>>(
        csr_row, start2, h, dinv, b2, x2, batch, pooled, cntg);
    // ---- layer 3 ----
    gemm_kernel<64><<<gemm_blocks, 256, 0, stream>>>(x2, W3, dinv, h);
    aggregate_kernel<false, false, 128><<<agg_blocks, 256, 0, stream>>>(
        csr_row, start2, h, dinv, b3, nullptr, batch, pooled, cntg);
    // ---- head ----
    head_kernel<<<N_GRAPHS, 64, 0, stream>>>(pooled, cntg, Wf, bf, out);
}